// Round 3
// baseline (28989.630 us; speedup 1.0000x reference)
//
#include <hip/hip_runtime.h>

#define TT 8192
#define DD 2048
#define NWG 256
#define RPW 8           // rows of h per workgroup
#define NTH 256

typedef unsigned long long u64;
#define SIGN2 0x8000000080000000ULL

// ---------------- Phase 1: pre = x @ W1^T + b1  (M=TT, N=DD, K=DD) ----------
#define BM 128
#define BN 128
#define BK 16

__global__ __launch_bounds__(NTH)
void gemm_abt_bias(const float* __restrict__ A, const float* __restrict__ B,
                   const float* __restrict__ bias, float* __restrict__ C,
                   int M, int N, int K) {
  __shared__ float As[BK][BM + 4];
  __shared__ float Bs[BK][BN + 4];
  const int ntile = N / BN;
  const int bn = blockIdx.x % ntile;
  const int bm = blockIdx.x / ntile;
  const int tid = (int)threadIdx.x;
  const int tx = tid & 15;
  const int ty = tid >> 4;

  float acc[8][8];
#pragma unroll
  for (int i = 0; i < 8; ++i)
#pragma unroll
    for (int j = 0; j < 8; ++j) acc[i][j] = 0.f;

  for (int kt = 0; kt < K; kt += BK) {
#pragma unroll
    for (int i = 0; i < 2; ++i) {
      int f = tid + i * 256;
      int row = f >> 2, c4 = f & 3;
      const float4 av = *(const float4*)(A + (size_t)(bm * BM + row) * K + kt + c4 * 4);
      As[c4 * 4 + 0][row] = av.x; As[c4 * 4 + 1][row] = av.y;
      As[c4 * 4 + 2][row] = av.z; As[c4 * 4 + 3][row] = av.w;
      const float4 bv = *(const float4*)(B + (size_t)(bn * BN + row) * K + kt + c4 * 4);
      Bs[c4 * 4 + 0][row] = bv.x; Bs[c4 * 4 + 1][row] = bv.y;
      Bs[c4 * 4 + 2][row] = bv.z; Bs[c4 * 4 + 3][row] = bv.w;
    }
    __syncthreads();
#pragma unroll
    for (int kk = 0; kk < BK; ++kk) {
      float a[8], b[8];
      *(float4*)&a[0] = *(const float4*)&As[kk][ty * 8];
      *(float4*)&a[4] = *(const float4*)&As[kk][ty * 8 + 4];
      *(float4*)&b[0] = *(const float4*)&Bs[kk][tx * 8];
      *(float4*)&b[4] = *(const float4*)&Bs[kk][tx * 8 + 4];
#pragma unroll
      for (int i = 0; i < 8; ++i)
#pragma unroll
        for (int j = 0; j < 8; ++j) acc[i][j] += a[i] * b[j];
    }
    __syncthreads();
  }

  const int col0 = bn * BN + tx * 8;
  const float4 bv0 = *(const float4*)(bias + col0);
  const float4 bv1 = *(const float4*)(bias + col0 + 4);
#pragma unroll
  for (int i = 0; i < 8; ++i) {
    float* crow = C + (size_t)(bm * BM + ty * 8 + i) * N + col0;
    float4 v0 = { acc[i][0] + bv0.x, acc[i][1] + bv0.y, acc[i][2] + bv0.z, acc[i][3] + bv0.w };
    float4 v1 = { acc[i][4] + bv1.x, acc[i][5] + bv1.y, acc[i][6] + bv1.z, acc[i][7] + bv1.w };
    *(float4*)(crow) = v0;
    *(float4*)(crow + 4) = v1;
  }
}

// ---------------- Phase 2: persistent recurrent kernel ----------------------
__device__ __forceinline__ float wave_sum(float v) {
#pragma unroll
  for (int off = 32; off > 0; off >>= 1) v += __shfl_down(v, off, 64);
  return v;
}

__device__ __forceinline__ u64 aload(const u64* p) {
  return __hip_atomic_load(p, __ATOMIC_RELAXED, __HIP_MEMORY_SCOPE_AGENT);
}
__device__ __forceinline__ void astore(u64* p, u64 v) {
  __hip_atomic_store(p, v, __ATOMIC_RELAXED, __HIP_MEMORY_SCOPE_AGENT);
}

// Sync protocol (2 LLC hops/step, all relaxed agent-scope; no acquire/release
// -> no buffer_inv/wbl2 storms):
//  * h is ReLU output (>=0) -> sign bits are free tag space. h_t lives in slot
//    (t&1); successive tenants of a slot are 2 steps apart, so tag=(t>>1)&1
//    alternates per tenant. Producer packs 2 floats into one 8B atomic with
//    both sign bits = tag: readiness travels WITH the data.
//  * Every thread polls ITS 32B chunk's tags directly (4x u64). Detection and
//    data arrive in the same LLC response -> producer-store + poll-load is the
//    whole inter-WG chain.
//  * Slot-reuse/ABA safety (inductive): any chunk of h_{t+2} existing implies
//    every WG stored h_{t+1}, which implies every wave of every WG finished
//    its GEMV on h_t (its store is part of its WG's chunk, and pollers check
//    all 4 tags of a chunk).
//  * Anti-poison init: slot0 = 0x00 (tag 0; first tenant h_2 expects tag 1),
//    slot1 = 0xAA (tag 1; first tenant h_1 expects tag 0).
__global__ void __launch_bounds__(NTH, 1)
recurrent_kernel(const float* __restrict__ h0,
                 const float* __restrict__ W2,
                 const float* __restrict__ b2,
                 const float* __restrict__ pre,
                 const float* __restrict__ Wf,
                 const float* __restrict__ bf,
                 float* __restrict__ out,
                 float* hbuf) {    // 2*DD floats, double-buffered h
  __shared__ float hs[2][DD];      // 16 KB double-buffered h stage

  const int wg   = (int)blockIdx.x;
  const int tid  = (int)threadIdx.x;
  const int lane = tid & 63;
  const int wave = tid >> 6;
  const int gr0 = wg * RPW + 2 * wave;   // global h-row ids this wave produces
  const int gr1 = gr0 + 1;

  // W2 rows pinned in REGISTERS (64 VGPRs/lane), k-interleaved so the h read
  // per j is a contiguous ds_read_b128: lane owns k = j*256 + 4*lane + i.
  float w2a[32], w2b[32];
#pragma unroll
  for (int j = 0; j < 8; ++j) {
    *(float4*)&w2a[4 * j] = *(const float4*)(W2 + (size_t)gr0 * DD + j * 256 + 4 * lane);
    *(float4*)&w2b[4 * j] = *(const float4*)(W2 + (size_t)gr1 * DD + j * 256 + 4 * lane);
  }
  const float b2r0 = b2[gr0];
  const float b2r1 = b2[gr1];

  u64* const hb0 = (u64*)hbuf;          // slot 0
  u64* const hb1 = (u64*)(hbuf + DD);   // slot 1

  for (int t = 0; t < TT; ++t) {
    // This wave's pre values: issue the load before the poll loop (latency hides).
    float2 p2 = {0.f, 0.f};
    if (lane == 0) p2 = *(const float2*)(pre + (size_t)t * DD + wg * RPW + 2 * wave);

    float* hsb = hs[t & 1];
    if (t == 0) {
      ((float4*)hsb)[2 * tid]     = ((const float4*)h0)[2 * tid];
      ((float4*)hsb)[2 * tid + 1] = ((const float4*)h0)[2 * tid + 1];
    } else {
      u64* src = ((t & 1) ? hb1 : hb0) + 4 * tid;
      const u64 EXP = ((t >> 1) & 1) ? SIGN2 : 0ULL;
      u64 u0, u1, u2, u3;
      for (;;) {
        u0 = aload(src + 0); u1 = aload(src + 1);
        u2 = aload(src + 2); u3 = aload(src + 3);
        if (((((u0 ^ EXP) | (u1 ^ EXP)) | ((u2 ^ EXP) | (u3 ^ EXP))) & SIGN2) == 0ULL)
          break;
        __builtin_amdgcn_s_sleep(1);
      }
      u64* dst = (u64*)hsb + 4 * tid;
      dst[0] = u0 & ~SIGN2; dst[1] = u1 & ~SIGN2;
      dst[2] = u2 & ~SIGN2; dst[3] = u3 & ~SIGN2;
    }
    __syncthreads();   // the only barrier per step (hs is double-buffered)

    // GEMV: rows gr0, gr1 dot h, k-partitioned across lanes.
    float acc0 = 0.f, acc1 = 0.f;
#pragma unroll
    for (int j = 0; j < 8; ++j) {
      const float4 hv = *(const float4*)&hsb[j * 256 + 4 * lane];
      acc0 += w2a[4*j+0]*hv.x + w2a[4*j+1]*hv.y + w2a[4*j+2]*hv.z + w2a[4*j+3]*hv.w;
      acc1 += w2b[4*j+0]*hv.x + w2b[4*j+1]*hv.y + w2b[4*j+2]*hv.z + w2b[4*j+3]*hv.w;
    }
    acc0 = wave_sum(acc0);
    acc1 = wave_sum(acc1);

    if (lane == 0) {
      const float v0 = fmaxf(p2.x + b2r0 + acc0, 0.f);
      const float v1 = fmaxf(p2.y + b2r1 + acc1, 0.f);
      u64 u = (((u64)__float_as_uint(v1) << 32) | (u64)__float_as_uint(v0)) & ~SIGN2;
      if (((t + 1) >> 1) & 1) u |= SIGN2;   // tag for this slot-tenancy
      astore((((t + 1) & 1) ? hb1 : hb0) + (wg * 4 + wave), u);
    }
  }

  if (wg != 0) return;

  // WG0: out = Wf @ h_T + bf. h_8192 is in slot 0, tag (8192>>1)&1 = 0.
  {
    u64* src = hb0 + 4 * tid;
    u64 u0, u1, u2, u3;
    for (;;) {
      u0 = aload(src + 0); u1 = aload(src + 1);
      u2 = aload(src + 2); u3 = aload(src + 3);
      if ((((u0 | u1) | (u2 | u3)) & SIGN2) == 0ULL) break;   // expect tag 0
      __builtin_amdgcn_s_sleep(1);
    }
    u64* dst = (u64*)hs[0] + 4 * tid;
    dst[0] = u0; dst[1] = u1; dst[2] = u2; dst[3] = u3;
  }
  __syncthreads();
  float acc = 0.f;
#pragma unroll
  for (int j = 0; j < 8; ++j) {
    const float4 wv = *(const float4*)(Wf + (size_t)wave * DD + j * 256 + 4 * lane);
    const float4 hv = *(const float4*)&hs[0][j * 256 + 4 * lane];
    acc += wv.x * hv.x + wv.y * hv.y + wv.z * hv.z + wv.w * hv.w;
  }
  acc = wave_sum(acc);
  if (lane == 0) out[wave] = acc + bf[wave];
}

// ---------------- Launch ----------------------------------------------------
extern "C" void kernel_launch(void* const* d_in, const int* in_sizes, int n_in,
                              void* d_out, int out_size, void* d_ws, size_t ws_size,
                              hipStream_t stream) {
  const float* x  = (const float*)d_in[0];
  const float* h0 = (const float*)d_in[1];
  const float* W1 = (const float*)d_in[2];
  const float* b1 = (const float*)d_in[3];
  const float* W2 = (const float*)d_in[4];
  const float* b2 = (const float*)d_in[5];
  const float* Wf = (const float*)d_in[6];
  const float* bf = (const float*)d_in[7];
  float* out = (float*)d_out;

  // Workspace: pre (64 MB) | hbuf (16 KB)
  float* pre  = (float*)d_ws;
  float* hbuf = pre + (size_t)TT * DD;

  // Anti-poison slot init (see kernel comment).
  hipMemsetAsync(hbuf, 0x00, DD * sizeof(float), stream);        // slot0: tag 0
  hipMemsetAsync(hbuf + DD, 0xAA, DD * sizeof(float), stream);   // slot1: tag 1

  gemm_abt_bias<<<dim3((TT / BM) * (DD / BN)), dim3(NTH), 0, stream>>>(
      x, W1, b1, pre, TT, DD, DD);
  recurrent_kernel<<<dim3(NWG), dim3(NTH), 0, stream>>>(
      h0, W2, b2, pre, Wf, bf, out, hbuf);
}

// Round 4
// 27420.425 us; speedup vs baseline: 1.0572x; 1.0572x over previous
//
#include <hip/hip_runtime.h>

#define TT 8192
#define DD 2048
#define NWG 256
#define RPW 8           // rows of h per workgroup
#define NTH 256
#define NREP 4          // replica h-buffers to spread LLC poll hotspot

typedef unsigned long long u64;
#define SIGN2 0x8000000080000000ULL

// ---------------- Phase 1: pre = x @ W1^T + b1  (M=TT, N=DD, K=DD) ----------
#define BM 128
#define BN 128
#define BK 16

__global__ __launch_bounds__(NTH)
void gemm_abt_bias(const float* __restrict__ A, const float* __restrict__ B,
                   const float* __restrict__ bias, float* __restrict__ C,
                   int M, int N, int K) {
  __shared__ float As[BK][BM + 4];
  __shared__ float Bs[BK][BN + 4];
  const int ntile = N / BN;
  const int bn = blockIdx.x % ntile;
  const int bm = blockIdx.x / ntile;
  const int tid = (int)threadIdx.x;
  const int tx = tid & 15;
  const int ty = tid >> 4;

  float acc[8][8];
#pragma unroll
  for (int i = 0; i < 8; ++i)
#pragma unroll
    for (int j = 0; j < 8; ++j) acc[i][j] = 0.f;

  for (int kt = 0; kt < K; kt += BK) {
#pragma unroll
    for (int i = 0; i < 2; ++i) {
      int f = tid + i * 256;
      int row = f >> 2, c4 = f & 3;
      const float4 av = *(const float4*)(A + (size_t)(bm * BM + row) * K + kt + c4 * 4);
      As[c4 * 4 + 0][row] = av.x; As[c4 * 4 + 1][row] = av.y;
      As[c4 * 4 + 2][row] = av.z; As[c4 * 4 + 3][row] = av.w;
      const float4 bv = *(const float4*)(B + (size_t)(bn * BN + row) * K + kt + c4 * 4);
      Bs[c4 * 4 + 0][row] = bv.x; Bs[c4 * 4 + 1][row] = bv.y;
      Bs[c4 * 4 + 2][row] = bv.z; Bs[c4 * 4 + 3][row] = bv.w;
    }
    __syncthreads();
#pragma unroll
    for (int kk = 0; kk < BK; ++kk) {
      float a[8], b[8];
      *(float4*)&a[0] = *(const float4*)&As[kk][ty * 8];
      *(float4*)&a[4] = *(const float4*)&As[kk][ty * 8 + 4];
      *(float4*)&b[0] = *(const float4*)&Bs[kk][tx * 8];
      *(float4*)&b[4] = *(const float4*)&Bs[kk][tx * 8 + 4];
#pragma unroll
      for (int i = 0; i < 8; ++i)
#pragma unroll
        for (int j = 0; j < 8; ++j) acc[i][j] += a[i] * b[j];
    }
    __syncthreads();
  }

  const int col0 = bn * BN + tx * 8;
  const float4 bv0 = *(const float4*)(bias + col0);
  const float4 bv1 = *(const float4*)(bias + col0 + 4);
#pragma unroll
  for (int i = 0; i < 8; ++i) {
    float* crow = C + (size_t)(bm * BM + ty * 8 + i) * N + col0;
    float4 v0 = { acc[i][0] + bv0.x, acc[i][1] + bv0.y, acc[i][2] + bv0.z, acc[i][3] + bv0.w };
    float4 v1 = { acc[i][4] + bv1.x, acc[i][5] + bv1.y, acc[i][6] + bv1.z, acc[i][7] + bv1.w };
    *(float4*)(crow) = v0;
    *(float4*)(crow + 4) = v1;
  }
}

// ---------------- Phase 2: persistent recurrent kernel ----------------------
__device__ __forceinline__ float wave_sum(float v) {
#pragma unroll
  for (int off = 32; off > 0; off >>= 1) v += __shfl_down(v, off, 64);
  return v;
}

__device__ __forceinline__ u64 aload(const u64* p) {
  return __hip_atomic_load(p, __ATOMIC_RELAXED, __HIP_MEMORY_SCOPE_AGENT);
}
__device__ __forceinline__ void astore(u64* p, u64 v) {
  __hip_atomic_store(p, v, __ATOMIC_RELAXED, __HIP_MEMORY_SCOPE_AGENT);
}

// Sync protocol (relaxed agent-scope only; parity tags in the sign bits of
// ReLU-nonnegative h values; slot = t&1, tag = (t>>1)&1):
//  * NREP replica h-buffers, layout [slot][rep][DD floats]. Consumer group
//    g = wg & (NREP-1) polls only replica g -> 64 pollers/line not 256.
//    Grouping is arbitrary (any assignment correct) - no placement assumption.
//  * GEMV is partitioned so each thread consumes EXACTLY the 32B chunk it
//    polls: wave w owns k in [512w,512w+512), lane l owns k [512w+8l,+8)
//    = u64s 4*tid..4*tid+3. W2 for all 8 WG-rows x that k-slice lives in 64
//    VGPRs. Detection -> FMA immediately, no LDS staging of h, no barrier
//    before compute. One barrier/step (cross-wave partial combine, double-
//    buffered LDS partials).
//  * ABA/slot-reuse safety (induction): any h_{t+2} chunk in any replica
//    implies its producer detected ALL of h_{t+1} in its replica, which
//    implies every WG stored h_{t+1} (to all replicas), which implies every
//    WG finished its step-t reads. Poll values are consumed from the same
//    registers that passed the tag check (no re-read).
//  * Anti-poison: slot0 = 0x00 (tag 0; first tenant h_2 expects tag 1),
//    slot1 = 0xAA (tag 1; first tenant h_1 expects tag 0).
__global__ void __launch_bounds__(NTH, 1)
recurrent_kernel(const float* __restrict__ h0,
                 const float* __restrict__ W2,
                 const float* __restrict__ b2,
                 const float* __restrict__ pre,
                 const float* __restrict__ Wf,
                 const float* __restrict__ bf,
                 float* __restrict__ out,
                 float* hbuf) {     // 2 * NREP * DD floats
  __shared__ float partial[2][4][8];   // [t&1][wave][row]
  __shared__ float hs[DD];             // epilogue only

  const int wg   = (int)blockIdx.x;
  const int tid  = (int)threadIdx.x;
  const int lane = tid & 63;
  const int wave = tid >> 6;
  const int grp  = wg & (NREP - 1);
  const int k0   = 512 * wave + 8 * lane;   // this thread's k-slice

  // W2 for all 8 WG rows x my 8 k values: 64 VGPRs, fully unrolled indexing.
  float w2[64];
#pragma unroll
  for (int r = 0; r < 8; ++r) {
    *(float4*)&w2[r * 8]     = *(const float4*)(W2 + (size_t)(wg * RPW + r) * DD + k0);
    *(float4*)&w2[r * 8 + 4] = *(const float4*)(W2 + (size_t)(wg * RPW + r) * DD + k0 + 4);
  }
  // Final-combine constants for threads 0..15 (c = tid>>2 -> rows 2c,2c+1).
  float b2a = 0.f, b2b = 0.f;
  if (tid < 16) {
    const int c = tid >> 2;
    b2a = b2[wg * RPW + 2 * c];
    b2b = b2[wg * RPW + 2 * c + 1];
  }

  u64* const hbU = (u64*)hbuf;   // u64 index: ((slot*NREP)+rep)*(DD/2) + i

  for (int t = 0; t < TT; ++t) {
    // Prefetch pre pair for the final combine (threads 0..15), pre-poll.
    float2 p2 = {0.f, 0.f};
    if (tid < 16) p2 = *(const float2*)(pre + (size_t)t * DD + wg * RPW + 2 * (tid >> 2));

    float h[8];
    if (t == 0) {
      const float4 a = *(const float4*)(h0 + k0);
      const float4 b = *(const float4*)(h0 + k0 + 4);
      h[0]=a.x; h[1]=a.y; h[2]=a.z; h[3]=a.w;
      h[4]=b.x; h[5]=b.y; h[6]=b.z; h[7]=b.w;
    } else {
      u64* src = hbU + (size_t)((t & 1) * NREP + grp) * (DD / 2) + 4 * tid;
      const u64 EXP = ((t >> 1) & 1) ? SIGN2 : 0ULL;
      u64 u0, u1, u2, u3;
      for (;;) {
        u0 = aload(src + 0); u1 = aload(src + 1);
        u2 = aload(src + 2); u3 = aload(src + 3);
        if (((((u0 ^ EXP) | (u1 ^ EXP)) | ((u2 ^ EXP) | (u3 ^ EXP))) & SIGN2) == 0ULL)
          break;
        __builtin_amdgcn_s_sleep(1);
      }
      u0 &= ~SIGN2; u1 &= ~SIGN2; u2 &= ~SIGN2; u3 &= ~SIGN2;
      h[0]=__uint_as_float((unsigned)u0); h[1]=__uint_as_float((unsigned)(u0>>32));
      h[2]=__uint_as_float((unsigned)u1); h[3]=__uint_as_float((unsigned)(u1>>32));
      h[4]=__uint_as_float((unsigned)u2); h[5]=__uint_as_float((unsigned)(u2>>32));
      h[6]=__uint_as_float((unsigned)u3); h[7]=__uint_as_float((unsigned)(u3>>32));
    }

    // Straight-from-registers partial GEMV: 8 rows x my 8 k.
    float acc[8];
#pragma unroll
    for (int r = 0; r < 8; ++r) acc[r] = 0.f;
#pragma unroll
    for (int i = 0; i < 8; ++i)
#pragma unroll
      for (int r = 0; r < 8; ++r) acc[r] += w2[r * 8 + i] * h[i];

#pragma unroll
    for (int r = 0; r < 8; ++r) acc[r] = wave_sum(acc[r]);

    if (lane == 0) {
      float4 v0 = { acc[0], acc[1], acc[2], acc[3] };
      float4 v1 = { acc[4], acc[5], acc[6], acc[7] };
      *(float4*)&partial[t & 1][wave][0] = v0;
      *(float4*)&partial[t & 1][wave][4] = v1;
    }
    __syncthreads();   // the only barrier per step (partials double-buffered)

    if (tid < 16) {
      const int c = tid >> 2, rp = tid & 3;
      const float* P = &partial[t & 1][0][0];
      const float s0 = P[0*8+2*c] + P[1*8+2*c] + P[2*8+2*c] + P[3*8+2*c];
      const float s1 = P[0*8+2*c+1] + P[1*8+2*c+1] + P[2*8+2*c+1] + P[3*8+2*c+1];
      const float v0 = fmaxf(p2.x + b2a + s0, 0.f);
      const float v1 = fmaxf(p2.y + b2b + s1, 0.f);
      u64 u = (((u64)__float_as_uint(v1) << 32) | (u64)__float_as_uint(v0)) & ~SIGN2;
      if (((t + 1) >> 1) & 1) u |= SIGN2;
      astore(hbU + (size_t)(((t + 1) & 1) * NREP + rp) * (DD / 2) + wg * 4 + c, u);
    }
  }

  if (wg != 0) return;

  // WG0 epilogue: out = Wf @ h_TT + bf. h_8192: slot 0, rep 0, tag 0.
  {
    u64* src = hbU + 4 * tid;
    u64 u0, u1, u2, u3;
    for (;;) {
      u0 = aload(src + 0); u1 = aload(src + 1);
      u2 = aload(src + 2); u3 = aload(src + 3);
      if ((((u0 | u1) | (u2 | u3)) & SIGN2) == 0ULL) break;
      __builtin_amdgcn_s_sleep(1);
    }
    u64* dst = (u64*)hs + 4 * tid;
    dst[0] = u0; dst[1] = u1; dst[2] = u2; dst[3] = u3;
  }
  __syncthreads();
  float acc = 0.f;
#pragma unroll
  for (int j = 0; j < 8; ++j) {
    const float4 wv = *(const float4*)(Wf + (size_t)wave * DD + j * 256 + 4 * lane);
    const float4 hv = *(const float4*)&hs[j * 256 + 4 * lane];
    acc += wv.x * hv.x + wv.y * hv.y + wv.z * hv.z + wv.w * hv.w;
  }
  acc = wave_sum(acc);
  if (lane == 0) out[wave] = acc + bf[wave];
}

// ---------------- Launch ----------------------------------------------------
extern "C" void kernel_launch(void* const* d_in, const int* in_sizes, int n_in,
                              void* d_out, int out_size, void* d_ws, size_t ws_size,
                              hipStream_t stream) {
  const float* x  = (const float*)d_in[0];
  const float* h0 = (const float*)d_in[1];
  const float* W1 = (const float*)d_in[2];
  const float* b1 = (const float*)d_in[3];
  const float* W2 = (const float*)d_in[4];
  const float* b2 = (const float*)d_in[5];
  const float* Wf = (const float*)d_in[6];
  const float* bf = (const float*)d_in[7];
  float* out = (float*)d_out;

  // Workspace: pre (64 MB) | hbuf (2 slots x NREP x DD floats = 64 KB)
  float* pre  = (float*)d_ws;
  float* hbuf = pre + (size_t)TT * DD;

  // Anti-poison slot init (see kernel comment).
  hipMemsetAsync(hbuf, 0x00, NREP * DD * sizeof(float), stream);              // slot0
  hipMemsetAsync(hbuf + NREP * DD, 0xAA, NREP * DD * sizeof(float), stream);  // slot1

  gemm_abt_bias<<<dim3((TT / BM) * (DD / BN)), dim3(NTH), 0, stream>>>(
      x, W1, b1, pre, TT, DD, DD);
  recurrent_kernel<<<dim3(NWG), dim3(NTH), 0, stream>>>(
      h0, W2, b2, pre, Wf, bf, out, hbuf);
}